// Round 1
// baseline (1820.266 us; speedup 1.0000x reference)
//
#include <hip/hip_runtime.h>
#include <math.h>

#define CH 128
#define ETC 3
#define LN_EPS 1e-5f
#define L2_EPSC 1e-12f

#define TS 128
#define BKK 32
#define LDA 132   // padded LDS row (floats); 132*4=528 bytes, 16B-aligned rows

// ---------------------------------------------------------------------------
// GEMM: C[n][128] (op)= (A @ B) * scale + bias, A = [A0 | A1] (K=128 or 256)
// EPI: 0=write, 1=relu+write, 2=accumulate, 3=L2-rownorm init, 4=L2-rownorm acc
// ---------------------------------------------------------------------------
template<int EPI>
__global__ __launch_bounds__(256) void gemm128(
    const float* __restrict__ A0, const float* __restrict__ A1,
    const float* __restrict__ B0, const float* __restrict__ B1,
    const float* __restrict__ bias,
    float* __restrict__ C,
    int nrows, int K, float scale)
{
    __shared__ float As[BKK * LDA];
    __shared__ float Bs[BKK * LDA];
    const int tid = threadIdx.x;
    const int tx = tid & 15;
    const int ty = tid >> 4;
    const int row0 = blockIdx.x * TS;

    float acc[2][2][4][4] = {};  // [row-half][col-half][i][j]

    for (int k0 = 0; k0 < K; k0 += BKK) {
        const float* Asrc = (k0 < CH) ? A0 : A1;
        const float* Bsrc = (k0 < CH) ? B0 : B1;
        const int acol = k0 & (CH - 1);
        const int brow = k0 & (CH - 1);
        // A tile: As[k][m] = A[row0+m][k0+k]
        #pragma unroll
        for (int it = 0; it < 4; ++it) {
            int s = it * 256 + tid;
            int m = s >> 3;
            int kq = s & 7;
            float4 g = make_float4(0.f, 0.f, 0.f, 0.f);
            if (row0 + m < nrows)
                g = *(const float4*)&Asrc[(size_t)(row0 + m) * CH + acol + 4 * kq];
            As[(4 * kq + 0) * LDA + m] = g.x;
            As[(4 * kq + 1) * LDA + m] = g.y;
            As[(4 * kq + 2) * LDA + m] = g.z;
            As[(4 * kq + 3) * LDA + m] = g.w;
        }
        // B tile: Bs[k][j] = B[brow+k][j]
        #pragma unroll
        for (int it = 0; it < 4; ++it) {
            int s = it * 256 + tid;
            int k = s >> 5;
            int jq = s & 31;
            float4 g = *(const float4*)&Bsrc[(size_t)(brow + k) * CH + 4 * jq];
            *(float4*)&Bs[k * LDA + 4 * jq] = g;
        }
        __syncthreads();
        #pragma unroll
        for (int k = 0; k < BKK; ++k) {
            float4 a0 = *(const float4*)&As[k * LDA + 4 * ty];
            float4 a1 = *(const float4*)&As[k * LDA + 64 + 4 * ty];
            float4 b0 = *(const float4*)&Bs[k * LDA + 4 * tx];
            float4 b1 = *(const float4*)&Bs[k * LDA + 64 + 4 * tx];
            float av[2][4] = {{a0.x, a0.y, a0.z, a0.w}, {a1.x, a1.y, a1.z, a1.w}};
            float bv[2][4] = {{b0.x, b0.y, b0.z, b0.w}, {b1.x, b1.y, b1.z, b1.w}};
            #pragma unroll
            for (int rh = 0; rh < 2; ++rh)
                #pragma unroll
                for (int i = 0; i < 4; ++i)
                    #pragma unroll
                    for (int chh = 0; chh < 2; ++chh)
                        #pragma unroll
                        for (int j = 0; j < 4; ++j)
                            acc[rh][chh][i][j] = fmaf(av[rh][i], bv[chh][j], acc[rh][chh][i][j]);
        }
        __syncthreads();
    }

    // bias fragments (cols tx*4+j and 64+tx*4+j)
    float bfrag[2][4] = {};
    if (bias) {
        float4 b0v = *(const float4*)&bias[4 * tx];
        float4 b1v = *(const float4*)&bias[64 + 4 * tx];
        bfrag[0][0] = b0v.x; bfrag[0][1] = b0v.y; bfrag[0][2] = b0v.z; bfrag[0][3] = b0v.w;
        bfrag[1][0] = b1v.x; bfrag[1][1] = b1v.y; bfrag[1][2] = b1v.z; bfrag[1][3] = b1v.w;
    }

    float rowsc[2][4];
    if constexpr (EPI == 3 || EPI == 4) {
        __syncthreads();           // done reading tiles; reuse LDS
        float* red = As;           // [128][17]
        #pragma unroll
        for (int rh = 0; rh < 2; ++rh)
            #pragma unroll
            for (int i = 0; i < 4; ++i) {
                float p = 0.f;
                #pragma unroll
                for (int chh = 0; chh < 2; ++chh)
                    #pragma unroll
                    for (int j = 0; j < 4; ++j) {
                        float r = acc[rh][chh][i][j] * scale + bfrag[chh][j];
                        p += r * r;
                    }
                red[(rh * 64 + 4 * ty + i) * 17 + tx] = p;
            }
        __syncthreads();
        if (tid < 128) {
            float s = 0.f;
            #pragma unroll
            for (int c2 = 0; c2 < 16; ++c2) s += red[tid * 17 + c2];
            Bs[tid] = 1.0f / (3.0f * fmaxf(sqrtf(s), L2_EPSC));
        }
        __syncthreads();
        #pragma unroll
        for (int rh = 0; rh < 2; ++rh)
            #pragma unroll
            for (int i = 0; i < 4; ++i)
                rowsc[rh][i] = Bs[rh * 64 + 4 * ty + i];
    }

    #pragma unroll
    for (int rh = 0; rh < 2; ++rh)
        #pragma unroll
        for (int i = 0; i < 4; ++i) {
            int row = row0 + rh * 64 + 4 * ty + i;
            if (row >= nrows) continue;
            #pragma unroll
            for (int chh = 0; chh < 2; ++chh) {
                float4 v;
                float* vv = &v.x;
                #pragma unroll
                for (int j = 0; j < 4; ++j) {
                    float r = acc[rh][chh][i][j] * scale + bfrag[chh][j];
                    if constexpr (EPI == 1) r = fmaxf(r, 0.f);
                    if constexpr (EPI == 3 || EPI == 4) r *= rowsc[rh][i];
                    vv[j] = r;
                }
                float* cp = &C[(size_t)row * CH + chh * 64 + 4 * tx];
                if constexpr (EPI == 2 || EPI == 4) {
                    float4 c = *(const float4*)cp;
                    v.x += c.x; v.y += c.y; v.z += c.z; v.w += c.w;
                }
                *(float4*)cp = v;
            }
        }
}

// ---------------------------------------------------------------------------
// CSR gather-mean: agg[n] = mean over incoming edges of msg[src]
// one wave (64 lanes) per node, float2 per lane
// ---------------------------------------------------------------------------
__global__ __launch_bounds__(256) void agg_mean(
    const float* __restrict__ msg, const int* __restrict__ rowptr,
    const int* __restrict__ col, float* __restrict__ agg, int n)
{
    int gid = blockIdx.x * 256 + threadIdx.x;
    int node = gid >> 6;
    int lane = threadIdx.x & 63;
    if (node >= n) return;
    int s = rowptr[node], e = rowptr[node + 1];
    float ax = 0.f, ay = 0.f;
    for (int j = s; j < e; ++j) {
        int src = col[j];
        float2 v = *(const float2*)&msg[(size_t)src * CH + 2 * lane];
        ax += v.x; ay += v.y;
    }
    float inv = 1.0f / fmaxf((float)(e - s), 1.0f);
    *(float2*)&agg[(size_t)node * CH + 2 * lane] = make_float2(ax * inv, ay * inv);
}

// ---------------------------------------------------------------------------
// h = LN(relu(in)) * g + b  — one wave per row
// ---------------------------------------------------------------------------
__global__ __launch_bounds__(256) void relu_ln(
    const float* __restrict__ in, const float* __restrict__ g,
    const float* __restrict__ b, float* __restrict__ out, int n)
{
    int gid = blockIdx.x * 256 + threadIdx.x;
    int row = gid >> 6;
    int lane = threadIdx.x & 63;
    if (row >= n) return;
    float2 v = *(const float2*)&in[(size_t)row * CH + 2 * lane];
    v.x = fmaxf(v.x, 0.f); v.y = fmaxf(v.y, 0.f);
    float s1 = v.x + v.y;
    float s2 = v.x * v.x + v.y * v.y;
    #pragma unroll
    for (int m = 1; m < 64; m <<= 1) {
        s1 += __shfl_xor(s1, m, 64);
        s2 += __shfl_xor(s2, m, 64);
    }
    float mean = s1 * (1.0f / 128.0f);
    float var = s2 * (1.0f / 128.0f) - mean * mean;
    float rstd = rsqrtf(var + LN_EPS);
    float2 gg = *(const float2*)&g[2 * lane];
    float2 bb = *(const float2*)&b[2 * lane];
    float2 o;
    o.x = (v.x - mean) * rstd * gg.x + bb.x;
    o.y = (v.y - mean) * rstd * gg.y + bb.y;
    *(float2*)&out[(size_t)row * CH + 2 * lane] = o;
}

// ---------------------------------------------------------------------------
// CSR construction
// ---------------------------------------------------------------------------
__global__ __launch_bounds__(256) void hist_k(
    const int* __restrict__ edges, int* __restrict__ cnt, int E, int n)
{
    int t = blockIdx.y;
    int e = blockIdx.x * 256 + threadIdx.x;
    if (e >= E) return;
    int dst = edges[(size_t)t * 2 * E + E + e];
    atomicAdd(&cnt[t * n + dst], 1);
}

__global__ __launch_bounds__(256) void scan1_k(
    const int* __restrict__ cnt, int* __restrict__ bsum, int n, int nbs)
{
    int t = blockIdx.y, b = blockIdx.x;
    int i = b * 256 + threadIdx.x;
    int v = (i < n) ? cnt[t * n + i] : 0;
    #pragma unroll
    for (int m = 1; m < 64; m <<= 1) v += __shfl_xor(v, m, 64);
    __shared__ int wsum[4];
    if ((threadIdx.x & 63) == 0) wsum[threadIdx.x >> 6] = v;
    __syncthreads();
    if (threadIdx.x == 0) bsum[t * nbs + b] = wsum[0] + wsum[1] + wsum[2] + wsum[3];
}

__global__ __launch_bounds__(512) void scan2_k(int* __restrict__ bsum, int nbs, int nb)
{
    int t = blockIdx.x;
    int tid = threadIdx.x;
    __shared__ int sh[512];
    int v = (tid < nb) ? bsum[t * nbs + tid] : 0;
    sh[tid] = v;
    __syncthreads();
    for (int off = 1; off < 512; off <<= 1) {
        int x = (tid >= off) ? sh[tid - off] : 0;
        __syncthreads();
        sh[tid] += x;
        __syncthreads();
    }
    if (tid < nb) bsum[t * nbs + tid] = sh[tid] - v;  // exclusive
}

__global__ __launch_bounds__(256) void scan3_k(
    const int* __restrict__ cnt, const int* __restrict__ bsum,
    int* __restrict__ rowptr, int n, int nbs)
{
    int t = blockIdx.y, b = blockIdx.x;
    int tid = threadIdx.x;
    int i = b * 256 + tid;
    __shared__ int sh[256];
    int v = (i < n) ? cnt[t * n + i] : 0;
    sh[tid] = v;
    __syncthreads();
    for (int off = 1; off < 256; off <<= 1) {
        int x = (tid >= off) ? sh[tid - off] : 0;
        __syncthreads();
        sh[tid] += x;
        __syncthreads();
    }
    int excl = sh[tid] - v + bsum[t * nbs + b];
    if (i < n) rowptr[(size_t)t * (n + 1) + i] = excl;
    if (i == n - 1) rowptr[(size_t)t * (n + 1) + n] = excl + v;
}

__global__ __launch_bounds__(256) void fill_k(
    const int* __restrict__ edges, const int* __restrict__ rowptr,
    int* __restrict__ cnt2, int* __restrict__ colbuf, int E, int n)
{
    int t = blockIdx.y;
    int e = blockIdx.x * 256 + threadIdx.x;
    if (e >= E) return;
    int src = edges[(size_t)t * 2 * E + e];
    int dst = edges[(size_t)t * 2 * E + E + e];
    int pos = rowptr[(size_t)t * (n + 1) + dst] + atomicAdd(&cnt2[t * n + dst], 1);
    colbuf[(size_t)t * E + pos] = src;
}

// Wrs = sum_t Wr[l,t]; bls = (sum_t bl[l,t]) / 3
__global__ __launch_bounds__(256) void wsum_k(
    const float* __restrict__ Wr_l, const float* __restrict__ bl_l,
    float* __restrict__ Wrs, float* __restrict__ bls)
{
    int i = blockIdx.x * 256 + threadIdx.x;
    if (i < CH * CH) Wrs[i] = Wr_l[i] + Wr_l[CH * CH + i] + Wr_l[2 * CH * CH + i];
    if (i < CH) bls[i] = (bl_l[i] + bl_l[CH + i] + bl_l[2 * CH + i]) * (1.0f / 3.0f);
}

// ---------------------------------------------------------------------------
extern "C" void kernel_launch(void* const* d_in, const int* in_sizes, int n_in,
                              void* d_out, int out_size, void* d_ws, size_t ws_size,
                              hipStream_t stream) {
    const float* x    = (const float*)d_in[0];
    const int*   edges= (const int*)d_in[1];
    const float* Wp   = (const float*)d_in[2];
    const float* bp   = (const float*)d_in[3];
    const float* Wl0  = (const float*)d_in[4];
    const float* bl0  = (const float*)d_in[5];
    const float* Wr0  = (const float*)d_in[6];
    const float* Wl   = (const float*)d_in[7];
    const float* bl   = (const float*)d_in[8];
    const float* Wr   = (const float*)d_in[9];
    const float* ln_g = (const float*)d_in[10];
    const float* ln_b = (const float*)d_in[11];
    float* out = (float*)d_out;

    const int n = in_sizes[0] / CH;          // 100000
    const int E = in_sizes[1] / (2 * ETC);   // 500000
    const int NBS = 512;                     // bsum stride
    const int nb = (n + 255) / 256;          // scan blocks per type

    // workspace layout (fp32/int32)
    float* hs   = (float*)d_ws;              // n*128 — proj buffer, later h
    float* hacc = hs + (size_t)n * CH;       // n*128
    float* agg  = hacc + (size_t)n * CH;     // n*128
    int* cnt    = (int*)(agg + (size_t)n * CH);   // 3n (reused as fill counter)
    int* rowptr = cnt + (size_t)ETC * n;          // 3*(n+1)
    int* colbuf = rowptr + (size_t)ETC * (n + 1); // 3*E
    int* bsum   = colbuf + (size_t)ETC * E;       // 3*NBS
    float* Wrs  = (float*)(bsum + ETC * NBS);     // 128*128
    float* bls  = Wrs + CH * CH;                  // 128

    const dim3 b256(256);
    const int gb = (n + TS - 1) / TS;        // GEMM blocks (782)
    const int gw = (n + 3) / 4;              // wave-per-row blocks (25000)
    const dim3 ge((E + 255) / 256, ETC);
    const dim3 gs(nb, ETC);

    // ---- CSR build (per edge type) ----
    hipMemsetAsync(cnt, 0, (size_t)ETC * n * sizeof(int), stream);
    hist_k<<<ge, b256, 0, stream>>>(edges, cnt, E, n);
    scan1_k<<<gs, b256, 0, stream>>>(cnt, bsum, n, NBS);
    scan2_k<<<ETC, 512, 0, stream>>>(bsum, NBS, nb);
    scan3_k<<<gs, b256, 0, stream>>>(cnt, bsum, rowptr, n, NBS);
    hipMemsetAsync(cnt, 0, (size_t)ETC * n * sizeof(int), stream);
    fill_k<<<ge, b256, 0, stream>>>(edges, rowptr, cnt, colbuf, E, n);

    // ---- layer 0 (project=True, normalize=True) ----
    for (int t = 0; t < ETC; ++t) {
        gemm128<1><<<gb, b256, 0, stream>>>(x, nullptr, Wp + (size_t)t * CH * CH, nullptr,
                                            bp + t * CH, hs, n, CH, 1.0f);
        agg_mean<<<gw, b256, 0, stream>>>(hs, rowptr + (size_t)t * (n + 1),
                                          colbuf + (size_t)t * E, agg, n);
        if (t == 0)
            gemm128<3><<<gb, b256, 0, stream>>>(agg, x, Wl0 + (size_t)t * CH * CH,
                                                Wr0 + (size_t)t * CH * CH, bl0 + t * CH,
                                                hacc, n, 2 * CH, 1.0f);
        else
            gemm128<4><<<gb, b256, 0, stream>>>(agg, x, Wl0 + (size_t)t * CH * CH,
                                                Wr0 + (size_t)t * CH * CH, bl0 + t * CH,
                                                hacc, n, 2 * CH, 1.0f);
    }
    relu_ln<<<gw, b256, 0, stream>>>(hacc, ln_g, ln_b, hs, n);

    // ---- layers 1..2 (fold Wr across edge types; mean = /3 in epilogue) ----
    for (int l = 0; l < 2; ++l) {
        float* dest = (l == 0) ? hacc : out;
        wsum_k<<<64, b256, 0, stream>>>(Wr + (size_t)l * ETC * CH * CH,
                                        bl + (size_t)l * ETC * CH, Wrs, bls);
        gemm128<0><<<gb, b256, 0, stream>>>(hs, nullptr, Wrs, nullptr, bls,
                                            dest, n, CH, 1.0f / 3.0f);
        for (int t = 0; t < ETC; ++t) {
            agg_mean<<<gw, b256, 0, stream>>>(hs, rowptr + (size_t)t * (n + 1),
                                              colbuf + (size_t)t * E, agg, n);
            gemm128<2><<<gb, b256, 0, stream>>>(agg, nullptr,
                                                Wl + ((size_t)l * ETC + t) * CH * CH, nullptr,
                                                nullptr, dest, n, CH, 1.0f / 3.0f);
        }
        if (l == 0)
            relu_ln<<<gw, b256, 0, stream>>>(hacc, ln_g + CH, ln_b + CH, hs, n);
    }
}

// Round 2
// 1069.299 us; speedup vs baseline: 1.7023x; 1.7023x over previous
//
#include <hip/hip_runtime.h>
#include <math.h>

#define CH 128
#define ETC 3
#define LN_EPS 1e-5f

typedef unsigned short u16;
typedef unsigned int u32;
typedef __attribute__((ext_vector_type(8))) short short8;
typedef __attribute__((ext_vector_type(4))) float f32x4;

__device__ __forceinline__ u16 f2bf(float f) {
    u32 u = __float_as_uint(f);
    u += 0x7FFFu + ((u >> 16) & 1u);
    return (u16)(u >> 16);
}
__device__ __forceinline__ float bflo(u32 u) { return __uint_as_float(u << 16); }
__device__ __forceinline__ float bfhi(u32 u) { return __uint_as_float(u & 0xFFFF0000u); }

__device__ __forceinline__ f32x4 mfma16(short8 a, short8 b, f32x4 c) {
    return __builtin_amdgcn_mfma_f32_16x16x32_bf16(a, b, c, 0, 0, 0);
}
__device__ __forceinline__ short8 ld8(const u16* p) { return *(const short8*)p; }

// ---------------------------------------------------------------------------
// Pack weights: fp32 -> bf16, swizzled to per-lane MFMA B-fragment order.
// Layout: [mat][s(4)][nt(8)][lane(64)][j(8)]   (mat stride = CH*CH u16)
// mats 0-2: Wp_t | 3-8: (Wl0_t, Wr0_t) pairs | 9-11: Wl[0,t]/3 | 12: sum(Wr[0,t])/3
// | 13-15: Wl[1,t]/3 | 16: sum(Wr[1,t])/3.  Also bls[2][128] = sum_t bl[l,t]/3.
// B fragment: lane(q=lane>>4,c=lane&15) holds B[k=s*32+q*8+j][n=nt*16+c]
// ---------------------------------------------------------------------------
__global__ __launch_bounds__(256) void pack_w(
    const float* __restrict__ Wp, const float* __restrict__ Wl0,
    const float* __restrict__ Wr0, const float* __restrict__ Wl,
    const float* __restrict__ Wr, const float* __restrict__ bl,
    u16* __restrict__ Bswz, float* __restrict__ bls)
{
    if (blockIdx.x == 0) {
        int l = threadIdx.x >> 7, i = threadIdx.x & 127;
        bls[threadIdx.x] = (bl[((size_t)l * ETC + 0) * CH + i] +
                            bl[((size_t)l * ETC + 1) * CH + i] +
                            bl[((size_t)l * ETC + 2) * CH + i]) * (1.f / 3.f);
    }
    int grp = blockIdx.x * 256 + threadIdx.x;   // ((mat*4+s)*8+nt)*64 + lane
    if (grp >= 17 * 2048) return;
    int lane = grp & 63;
    int t1 = grp >> 6;
    int nt = t1 & 7, t2 = t1 >> 3;
    int s = t2 & 3, mat = t2 >> 2;
    int q = lane >> 4, c = lane & 15;
    int nn = nt * 16 + c;

    const float* s0;
    const float* s1 = nullptr;
    const float* s2 = nullptr;
    float scale = 1.f;
    if (mat < 3) {
        s0 = Wp + (size_t)mat * CH * CH;
    } else if (mat < 9) {
        int t = (mat - 3) >> 1;
        s0 = ((mat - 3) & 1) ? Wr0 + (size_t)t * CH * CH : Wl0 + (size_t)t * CH * CH;
    } else {
        int l = (mat < 13) ? 0 : 1;
        int mm = mat - (l ? 13 : 9);
        scale = 1.f / 3.f;
        if (mm < 3) s0 = Wl + ((size_t)l * ETC + mm) * CH * CH;
        else {
            s0 = Wr + ((size_t)l * ETC + 0) * CH * CH;
            s1 = s0 + CH * CH;
            s2 = s1 + CH * CH;
        }
    }
    short8 o;
    #pragma unroll
    for (int j = 0; j < 8; ++j) {
        int k = s * 32 + q * 8 + j;
        float v = s0[(size_t)k * CH + nn];
        if (s1) v += s1[(size_t)k * CH + nn] + s2[(size_t)k * CH + nn];
        o[j] = (short)f2bf(v * scale);
    }
    *(short8*)&Bswz[(size_t)grp * 8] = o;
}

// ---------------------------------------------------------------------------
__global__ __launch_bounds__(256) void cast_x(
    const float* __restrict__ x, u16* __restrict__ xb, int total)
{
    int i = (blockIdx.x * 256 + threadIdx.x) * 8;
    if (i >= total) return;
    short8 o;
    #pragma unroll
    for (int j = 0; j < 8; ++j) o[j] = (short)f2bf(x[i + j]);
    *(short8*)&xb[i] = o;
}

// ---------------------------------------------------------------------------
// proj: hs = bf16(relu(x @ Wp_t + bp_t)), MFMA, no LDS.
// block = 256 thr = 4 waves; wave w: rows [blk*128 + w*32, +32)
// ---------------------------------------------------------------------------
__global__ __launch_bounds__(256) void proj_k(
    const u16* __restrict__ xb, const u16* __restrict__ Bs,
    const float* __restrict__ bp, u16* __restrict__ hs, int nrows)
{
    const int tid = threadIdx.x;
    const int w = tid >> 6, lane = tid & 63;
    const int q = lane >> 4, c = lane & 15;
    const int rb = blockIdx.x * 128 + w * 32;

    f32x4 acc[2][8] = {};
    #pragma unroll
    for (int s = 0; s < 4; ++s) {
        short8 a0 = ld8(&xb[(size_t)(rb + c) * CH + s * 32 + q * 8]);
        short8 a1 = ld8(&xb[(size_t)(rb + 16 + c) * CH + s * 32 + q * 8]);
        #pragma unroll
        for (int nt = 0; nt < 8; ++nt) {
            short8 bv = ld8(&Bs[((size_t)(s * 8 + nt) * 64 + lane) * 8]);
            acc[0][nt] = mfma16(a0, bv, acc[0][nt]);
            acc[1][nt] = mfma16(a1, bv, acc[1][nt]);
        }
    }
    #pragma unroll
    for (int nt = 0; nt < 8; ++nt) {
        float bpv = bp[nt * 16 + c];
        #pragma unroll
        for (int mt = 0; mt < 2; ++mt)
            #pragma unroll
            for (int r = 0; r < 4; ++r) {
                int row = rb + mt * 16 + q * 4 + r;
                if (row < nrows)
                    hs[(size_t)row * CH + nt * 16 + c] = f2bf(fmaxf(acc[mt][nt][r] + bpv, 0.f));
            }
    }
}

// ---------------------------------------------------------------------------
// combine: full layer GEMM batch + fused epilogue.
// MODE 0: layer0 — per type t: acc = agg_t@Wl0_t + bl0_t + x@Wr0_t, row-L2-
//         normalize, res += acc/3; then relu+LN -> bf16
// MODE 1: mid — acc = sum_t agg_t@(Wl_t/3) + h@(sumWr/3) + bls; relu+LN -> bf16
// MODE 2: final — same acc; write fp32
// ---------------------------------------------------------------------------
template<int MODE>
__global__ __launch_bounds__(256) void combine_k(
    const u16* __restrict__ agg0, const u16* __restrict__ agg1,
    const u16* __restrict__ agg2, const u16* __restrict__ self,
    const u16* __restrict__ Bs, const float* __restrict__ bias,
    const float* __restrict__ lg, const float* __restrict__ lb,
    u16* __restrict__ outb, float* __restrict__ outf, int nrows)
{
    const int tid = threadIdx.x;
    const int w = tid >> 6, lane = tid & 63;
    const int q = lane >> 4, c = lane & 15;
    const int rb = blockIdx.x * 128 + w * 32;
    const u16* aggs[3] = {agg0, agg1, agg2};

    f32x4 acc[2][8] = {};
    f32x4 res[2][8] = {};

    if constexpr (MODE == 0) {
        for (int t = 0; t < ETC; ++t) {
            for (int half = 0; half < 2; ++half) {
                const u16* A = half ? self : aggs[t];
                const u16* Bm = Bs + (size_t)(2 * t + half) * CH * CH;
                #pragma unroll
                for (int s = 0; s < 4; ++s) {
                    short8 a0 = ld8(&A[(size_t)(rb + c) * CH + s * 32 + q * 8]);
                    short8 a1 = ld8(&A[(size_t)(rb + 16 + c) * CH + s * 32 + q * 8]);
                    #pragma unroll
                    for (int nt = 0; nt < 8; ++nt) {
                        short8 bv = ld8(&Bm[((size_t)(s * 8 + nt) * 64 + lane) * 8]);
                        acc[0][nt] = mfma16(a0, bv, acc[0][nt]);
                        acc[1][nt] = mfma16(a1, bv, acc[1][nt]);
                    }
                }
            }
            float bf[8];
            #pragma unroll
            for (int nt = 0; nt < 8; ++nt) bf[nt] = bias[t * CH + nt * 16 + c];
            #pragma unroll
            for (int mt = 0; mt < 2; ++mt) {
                float ss[4] = {0.f, 0.f, 0.f, 0.f};
                #pragma unroll
                for (int nt = 0; nt < 8; ++nt)
                    #pragma unroll
                    for (int r = 0; r < 4; ++r) {
                        float v = acc[mt][nt][r] + bf[nt];
                        acc[mt][nt][r] = v;
                        ss[r] += v * v;
                    }
                #pragma unroll
                for (int m = 1; m < 16; m <<= 1)
                    #pragma unroll
                    for (int r = 0; r < 4; ++r) ss[r] += __shfl_xor(ss[r], m, 64);
                float sc[4];
                #pragma unroll
                for (int r = 0; r < 4; ++r)
                    sc[r] = 1.f / (3.f * fmaxf(sqrtf(ss[r]), 1e-12f));
                #pragma unroll
                for (int nt = 0; nt < 8; ++nt)
                    #pragma unroll
                    for (int r = 0; r < 4; ++r)
                        res[mt][nt][r] += acc[mt][nt][r] * sc[r];
            }
            #pragma unroll
            for (int mt = 0; mt < 2; ++mt)
                #pragma unroll
                for (int nt = 0; nt < 8; ++nt) acc[mt][nt] = (f32x4){0.f, 0.f, 0.f, 0.f};
        }
    } else {
        for (int m4 = 0; m4 < 4; ++m4) {
            const u16* A = (m4 < 3) ? aggs[m4] : self;
            const u16* Bm = Bs + (size_t)m4 * CH * CH;
            #pragma unroll
            for (int s = 0; s < 4; ++s) {
                short8 a0 = ld8(&A[(size_t)(rb + c) * CH + s * 32 + q * 8]);
                short8 a1 = ld8(&A[(size_t)(rb + 16 + c) * CH + s * 32 + q * 8]);
                #pragma unroll
                for (int nt = 0; nt < 8; ++nt) {
                    short8 bv = ld8(&Bm[((size_t)(s * 8 + nt) * 64 + lane) * 8]);
                    acc[0][nt] = mfma16(a0, bv, acc[0][nt]);
                    acc[1][nt] = mfma16(a1, bv, acc[1][nt]);
                }
            }
        }
        #pragma unroll
        for (int nt = 0; nt < 8; ++nt) {
            float bv = bias[nt * 16 + c];
            #pragma unroll
            for (int mt = 0; mt < 2; ++mt)
                #pragma unroll
                for (int r = 0; r < 4; ++r) res[mt][nt][r] = acc[mt][nt][r] + bv;
        }
    }

    if constexpr (MODE == 2) {
        #pragma unroll
        for (int nt = 0; nt < 8; ++nt)
            #pragma unroll
            for (int mt = 0; mt < 2; ++mt)
                #pragma unroll
                for (int r = 0; r < 4; ++r) {
                    int row = rb + mt * 16 + q * 4 + r;
                    if (row < nrows) outf[(size_t)row * CH + nt * 16 + c] = res[mt][nt][r];
                }
        return;
    }

    // relu + LayerNorm (rows live within quads: shuffle over 16-lane groups)
    #pragma unroll
    for (int mt = 0; mt < 2; ++mt) {
        float s1[4] = {0.f, 0.f, 0.f, 0.f}, s2[4] = {0.f, 0.f, 0.f, 0.f};
        #pragma unroll
        for (int nt = 0; nt < 8; ++nt)
            #pragma unroll
            for (int r = 0; r < 4; ++r) {
                float v = fmaxf(res[mt][nt][r], 0.f);
                res[mt][nt][r] = v;
                s1[r] += v;
                s2[r] += v * v;
            }
        #pragma unroll
        for (int m = 1; m < 16; m <<= 1)
            #pragma unroll
            for (int r = 0; r < 4; ++r) {
                s1[r] += __shfl_xor(s1[r], m, 64);
                s2[r] += __shfl_xor(s2[r], m, 64);
            }
        float mu[4], rs[4];
        #pragma unroll
        for (int r = 0; r < 4; ++r) {
            mu[r] = s1[r] * (1.f / 128.f);
            float var = s2[r] * (1.f / 128.f) - mu[r] * mu[r];
            rs[r] = rsqrtf(var + LN_EPS);
        }
        #pragma unroll
        for (int nt = 0; nt < 8; ++nt) {
            float gv = lg[nt * 16 + c], bv = lb[nt * 16 + c];
            #pragma unroll
            for (int r = 0; r < 4; ++r) {
                int row = rb + mt * 16 + q * 4 + r;
                if (row < nrows)
                    outb[(size_t)row * CH + nt * 16 + c] =
                        f2bf((res[mt][nt][r] - mu[r]) * rs[r] * gv + bv);
            }
        }
    }
}

// ---------------------------------------------------------------------------
// CSR gather-mean (bf16): one wave per node, one u32 (2 bf16) per lane
// ---------------------------------------------------------------------------
__global__ __launch_bounds__(256) void agg_k(
    const u16* __restrict__ msg, const int* __restrict__ rowptr,
    const int* __restrict__ col, u16* __restrict__ agg, int n)
{
    int gid = blockIdx.x * 256 + threadIdx.x;
    int node = gid >> 6, lane = threadIdx.x & 63;
    if (node >= n) return;
    int s = rowptr[node], e = rowptr[node + 1];
    const u32* m32 = (const u32*)msg;
    float ax = 0.f, ay = 0.f;
    for (int j = s; j < e; ++j) {
        int src = col[j];
        u32 v = m32[(size_t)src * 64 + lane];
        ax += bflo(v);
        ay += bfhi(v);
    }
    float inv = 1.f / (float)max(e - s, 1);
    u32 o = (u32)f2bf(ax * inv) | ((u32)f2bf(ay * inv) << 16);
    ((u32*)agg)[(size_t)node * 64 + lane] = o;
}

// ---------------------------------------------------------------------------
// CSR construction (unchanged from R1)
// ---------------------------------------------------------------------------
__global__ __launch_bounds__(256) void hist_k(
    const int* __restrict__ edges, int* __restrict__ cnt, int E, int n)
{
    int t = blockIdx.y;
    int e = blockIdx.x * 256 + threadIdx.x;
    if (e >= E) return;
    int dst = edges[(size_t)t * 2 * E + E + e];
    atomicAdd(&cnt[t * n + dst], 1);
}

__global__ __launch_bounds__(256) void scan1_k(
    const int* __restrict__ cnt, int* __restrict__ bsum, int n, int nbs)
{
    int t = blockIdx.y, b = blockIdx.x;
    int i = b * 256 + threadIdx.x;
    int v = (i < n) ? cnt[t * n + i] : 0;
    #pragma unroll
    for (int m = 1; m < 64; m <<= 1) v += __shfl_xor(v, m, 64);
    __shared__ int wsum[4];
    if ((threadIdx.x & 63) == 0) wsum[threadIdx.x >> 6] = v;
    __syncthreads();
    if (threadIdx.x == 0) bsum[t * nbs + b] = wsum[0] + wsum[1] + wsum[2] + wsum[3];
}

__global__ __launch_bounds__(512) void scan2_k(int* __restrict__ bsum, int nbs, int nb)
{
    int t = blockIdx.x;
    int tid = threadIdx.x;
    __shared__ int sh[512];
    int v = (tid < nb) ? bsum[t * nbs + tid] : 0;
    sh[tid] = v;
    __syncthreads();
    for (int off = 1; off < 512; off <<= 1) {
        int x = (tid >= off) ? sh[tid - off] : 0;
        __syncthreads();
        sh[tid] += x;
        __syncthreads();
    }
    if (tid < nb) bsum[t * nbs + tid] = sh[tid] - v;
}

__global__ __launch_bounds__(256) void scan3_k(
    const int* __restrict__ cnt, const int* __restrict__ bsum,
    int* __restrict__ rowptr, int n, int nbs)
{
    int t = blockIdx.y, b = blockIdx.x;
    int tid = threadIdx.x;
    int i = b * 256 + tid;
    __shared__ int sh[256];
    int v = (i < n) ? cnt[t * n + i] : 0;
    sh[tid] = v;
    __syncthreads();
    for (int off = 1; off < 256; off <<= 1) {
        int x = (tid >= off) ? sh[tid - off] : 0;
        __syncthreads();
        sh[tid] += x;
        __syncthreads();
    }
    int excl = sh[tid] - v + bsum[t * nbs + b];
    if (i < n) rowptr[(size_t)t * (n + 1) + i] = excl;
    if (i == n - 1) rowptr[(size_t)t * (n + 1) + n] = excl + v;
}

__global__ __launch_bounds__(256) void fill_k(
    const int* __restrict__ edges, const int* __restrict__ rowptr,
    int* __restrict__ cnt2, int* __restrict__ colbuf, int E, int n)
{
    int t = blockIdx.y;
    int e = blockIdx.x * 256 + threadIdx.x;
    if (e >= E) return;
    int src = edges[(size_t)t * 2 * E + e];
    int dst = edges[(size_t)t * 2 * E + E + e];
    int pos = rowptr[(size_t)t * (n + 1) + dst] + atomicAdd(&cnt2[t * n + dst], 1);
    colbuf[(size_t)t * E + pos] = src;
}

// ---------------------------------------------------------------------------
extern "C" void kernel_launch(void* const* d_in, const int* in_sizes, int n_in,
                              void* d_out, int out_size, void* d_ws, size_t ws_size,
                              hipStream_t stream) {
    const float* x    = (const float*)d_in[0];
    const int*   edges= (const int*)d_in[1];
    const float* Wp   = (const float*)d_in[2];
    const float* bp   = (const float*)d_in[3];
    const float* Wl0  = (const float*)d_in[4];
    const float* bl0  = (const float*)d_in[5];
    const float* Wr0  = (const float*)d_in[6];
    const float* Wl   = (const float*)d_in[7];
    const float* bl   = (const float*)d_in[8];
    const float* Wr   = (const float*)d_in[9];
    const float* ln_g = (const float*)d_in[10];
    const float* ln_b = (const float*)d_in[11];
    float* out = (float*)d_out;

    const int n  = in_sizes[0] / CH;         // 100000
    const int E  = in_sizes[1] / (2 * ETC);  // 500000
    const int gb = (n + 127) / 128;          // 782 GEMM blocks
    const int npad = gb * 128;               // padded row count
    const int NBS = 512;
    const int nb = (n + 255) / 256;
    const size_t MS = (size_t)CH * CH;       // mat stride in u16

    // workspace layout
    char* p = (char*)d_ws;
    u16* xb   = (u16*)p;  p += (size_t)npad * CH * 2;
    u16* hs   = (u16*)p;  p += (size_t)npad * CH * 2;
    u16* agg  = (u16*)p;  p += (size_t)ETC * npad * CH * 2;
    u16* Bswz = (u16*)p;  p += 17 * MS * 2;
    float* bls = (float*)p; p += 256 * 4;
    int* cnt    = (int*)p;  p += (size_t)ETC * n * 4;
    int* rowptr = (int*)p;  p += (size_t)ETC * (n + 1) * 4;
    int* colbuf = (int*)p;  p += (size_t)ETC * E * 4;
    int* bsum   = (int*)p;

    const dim3 b256(256);
    const dim3 ge((E + 255) / 256, ETC);
    const dim3 gs(nb, ETC);
    const int gw = (n + 3) / 4;              // agg blocks (wave per node)

    // ---- CSR build ----
    hipMemsetAsync(cnt, 0, (size_t)ETC * n * sizeof(int), stream);
    hist_k<<<ge, b256, 0, stream>>>(edges, cnt, E, n);
    scan1_k<<<gs, b256, 0, stream>>>(cnt, bsum, n, NBS);
    scan2_k<<<ETC, 512, 0, stream>>>(bsum, NBS, nb);
    scan3_k<<<gs, b256, 0, stream>>>(cnt, bsum, rowptr, n, NBS);
    hipMemsetAsync(cnt, 0, (size_t)ETC * n * sizeof(int), stream);
    fill_k<<<ge, b256, 0, stream>>>(edges, rowptr, cnt, colbuf, E, n);

    // ---- pack weights + cast x ----
    pack_w<<<136, b256, 0, stream>>>(Wp, Wl0, Wr0, Wl, Wr, bl, Bswz, bls);
    cast_x<<<(n * CH / 8 + 255) / 256, b256, 0, stream>>>(x, xb, n * CH);

    // ---- layer 0: per-type proj + gather; then fused combine ----
    for (int t = 0; t < ETC; ++t) {
        proj_k<<<gb, b256, 0, stream>>>(xb, Bswz + (size_t)t * MS, bp + t * CH, hs, n);
        agg_k<<<gw, b256, 0, stream>>>(hs, rowptr + (size_t)t * (n + 1),
                                       colbuf + (size_t)t * E, agg + (size_t)t * npad * CH, n);
    }
    combine_k<0><<<gb, b256, 0, stream>>>(agg, agg + (size_t)npad * CH,
                                          agg + (size_t)2 * npad * CH, xb,
                                          Bswz + 3 * MS, bl0, ln_g, ln_b, hs, nullptr, n);

    // ---- layer 1 ----
    for (int t = 0; t < ETC; ++t)
        agg_k<<<gw, b256, 0, stream>>>(hs, rowptr + (size_t)t * (n + 1),
                                       colbuf + (size_t)t * E, agg + (size_t)t * npad * CH, n);
    combine_k<1><<<gb, b256, 0, stream>>>(agg, agg + (size_t)npad * CH,
                                          agg + (size_t)2 * npad * CH, hs,
                                          Bswz + 9 * MS, bls, ln_g + CH, ln_b + CH, hs, nullptr, n);

    // ---- layer 2 (final, fp32 out) ----
    for (int t = 0; t < ETC; ++t)
        agg_k<<<gw, b256, 0, stream>>>(hs, rowptr + (size_t)t * (n + 1),
                                       colbuf + (size_t)t * E, agg + (size_t)t * npad * CH, n);
    combine_k<2><<<gb, b256, 0, stream>>>(agg, agg + (size_t)npad * CH,
                                          agg + (size_t)2 * npad * CH, hs,
                                          Bswz + 13 * MS, bls + CH, nullptr, nullptr, nullptr, out, n);
}

// Round 3
// 813.783 us; speedup vs baseline: 2.2368x; 1.3140x over previous
//
#include <hip/hip_runtime.h>
#include <math.h>

#define CH 128
#define ETC 3
#define LN_EPS 1e-5f

typedef unsigned short u16;
typedef unsigned int u32;
typedef __attribute__((ext_vector_type(8))) short short8;
typedef __attribute__((ext_vector_type(4))) float f32x4;

__device__ __forceinline__ u16 f2bf(float f) {
    u32 u = __float_as_uint(f);
    u += 0x7FFFu + ((u >> 16) & 1u);
    return (u16)(u >> 16);
}
__device__ __forceinline__ float bflo(u32 u) { return __uint_as_float(u << 16); }
__device__ __forceinline__ float bfhi(u32 u) { return __uint_as_float(u & 0xFFFF0000u); }

__device__ __forceinline__ f32x4 mfma16(short8 a, short8 b, f32x4 c) {
    return __builtin_amdgcn_mfma_f32_16x16x32_bf16(a, b, c, 0, 0, 0);
}
__device__ __forceinline__ short8 ld8(const u16* p) { return *(const short8*)p; }

// ---------------------------------------------------------------------------
// Pack weights: fp32 -> bf16, swizzled to per-lane MFMA B-fragment order.
// Layout: [mat][s(4)][nt(8)][lane(64)][j(8)]   (mat stride = CH*CH u16)
// mats 0-2: Wp_t | 3-8: (Wl0_t, Wr0_t) pairs | 9-11: Wl[0,t]/3 | 12: sum(Wr[0,t])/3
// | 13-15: Wl[1,t]/3 | 16: sum(Wr[1,t])/3.  Also bls[2][128] = sum_t bl[l,t]/3.
// B fragment: lane(q=lane>>4,c=lane&15) holds B[k=s*32+q*8+j][n=nt*16+c]
// ---------------------------------------------------------------------------
__global__ __launch_bounds__(256) void pack_w(
    const float* __restrict__ Wp, const float* __restrict__ Wl0,
    const float* __restrict__ Wr0, const float* __restrict__ Wl,
    const float* __restrict__ Wr, const float* __restrict__ bl,
    u16* __restrict__ Bswz, float* __restrict__ bls)
{
    if (blockIdx.x == 0) {
        int l = threadIdx.x >> 7, i = threadIdx.x & 127;
        bls[threadIdx.x] = (bl[((size_t)l * ETC + 0) * CH + i] +
                            bl[((size_t)l * ETC + 1) * CH + i] +
                            bl[((size_t)l * ETC + 2) * CH + i]) * (1.f / 3.f);
    }
    int grp = blockIdx.x * 256 + threadIdx.x;   // ((mat*4+s)*8+nt)*64 + lane
    if (grp >= 17 * 2048) return;
    int lane = grp & 63;
    int t1 = grp >> 6;
    int nt = t1 & 7, t2 = t1 >> 3;
    int s = t2 & 3, mat = t2 >> 2;
    int q = lane >> 4, c = lane & 15;
    int nn = nt * 16 + c;

    const float* s0;
    const float* s1 = nullptr;
    const float* s2 = nullptr;
    float scale = 1.f;
    if (mat < 3) {
        s0 = Wp + (size_t)mat * CH * CH;
    } else if (mat < 9) {
        int t = (mat - 3) >> 1;
        s0 = ((mat - 3) & 1) ? Wr0 + (size_t)t * CH * CH : Wl0 + (size_t)t * CH * CH;
    } else {
        int l = (mat < 13) ? 0 : 1;
        int mm = mat - (l ? 13 : 9);
        scale = 1.f / 3.f;
        if (mm < 3) s0 = Wl + ((size_t)l * ETC + mm) * CH * CH;
        else {
            s0 = Wr + ((size_t)l * ETC + 0) * CH * CH;
            s1 = s0 + CH * CH;
            s2 = s1 + CH * CH;
        }
    }
    short8 o;
    #pragma unroll
    for (int j = 0; j < 8; ++j) {
        int k = s * 32 + q * 8 + j;
        float v = s0[(size_t)k * CH + nn];
        if (s1) v += s1[(size_t)k * CH + nn] + s2[(size_t)k * CH + nn];
        o[j] = (short)f2bf(v * scale);
    }
    *(short8*)&Bswz[(size_t)grp * 8] = o;
}

// ---------------------------------------------------------------------------
__global__ __launch_bounds__(256) void cast_x(
    const float* __restrict__ x, u16* __restrict__ xb, int total)
{
    int i = (blockIdx.x * 256 + threadIdx.x) * 8;
    if (i >= total) return;
    short8 o;
    #pragma unroll
    for (int j = 0; j < 8; ++j) o[j] = (short)f2bf(x[i + j]);
    *(short8*)&xb[i] = o;
}

// ---------------------------------------------------------------------------
// proj: hs = bf16(relu(x @ Wp_t + bp_t)) — 16-row waves, no LDS.
// ---------------------------------------------------------------------------
__global__ __launch_bounds__(256) void proj_k(
    const u16* __restrict__ xb, const u16* __restrict__ Bs,
    const float* __restrict__ bp, u16* __restrict__ hs, int nrows)
{
    const int wid = blockIdx.x * 4 + (threadIdx.x >> 6);
    const int lane = threadIdx.x & 63;
    const int q = lane >> 4, c = lane & 15;
    const int rb = wid * 16;

    short8 af[4];
    #pragma unroll
    for (int s = 0; s < 4; ++s)
        af[s] = ld8(&xb[(size_t)(rb + c) * CH + s * 32 + q * 8]);

    f32x4 acc[8] = {};
    #pragma unroll
    for (int s = 0; s < 4; ++s)
        #pragma unroll
        for (int nt = 0; nt < 8; ++nt) {
            short8 bv = ld8(&Bs[((size_t)(s * 8 + nt) * 64 + lane) * 8]);
            acc[nt] = mfma16(af[s], bv, acc[nt]);
        }

    #pragma unroll
    for (int nt = 0; nt < 8; ++nt) {
        float bpv = bp[nt * 16 + c];
        #pragma unroll
        for (int r = 0; r < 4; ++r) {
            int row = rb + q * 4 + r;
            if (row < nrows)
                hs[(size_t)row * CH + nt * 16 + c] = f2bf(fmaxf(acc[nt][r] + bpv, 0.f));
        }
    }
}

// ---------------------------------------------------------------------------
// combine: full layer GEMM batch + fused epilogue — 16-row waves.
// MODE 0: layer0 — per type t: acc = agg_t@Wl0_t + bl0_t + x@Wr0_t, row-L2-
//         normalize, res += acc/3; then relu+LN -> bf16
// MODE 1: mid — acc = sum_t agg_t@(Wl_t/3) + h@(sumWr/3) + bls; relu+LN -> bf16
// MODE 2: final — same acc; write fp32
// ---------------------------------------------------------------------------
template<int MODE>
__global__ __launch_bounds__(256) void combine_k(
    const u16* __restrict__ agg0, const u16* __restrict__ agg1,
    const u16* __restrict__ agg2, const u16* __restrict__ self,
    const u16* __restrict__ Bs, const float* __restrict__ bias,
    const float* __restrict__ lg, const float* __restrict__ lb,
    u16* __restrict__ outb, float* __restrict__ outf, int nrows)
{
    const int wid = blockIdx.x * 4 + (threadIdx.x >> 6);
    const int lane = threadIdx.x & 63;
    const int q = lane >> 4, c = lane & 15;
    const int rb = wid * 16;
    const u16* aggs[3] = {agg0, agg1, agg2};
    constexpr int NM = (MODE == 0) ? 6 : 4;

    f32x4 acc[8] = {};
    f32x4 res[8] = {};

    #pragma unroll
    for (int m = 0; m < NM; ++m) {
        const u16* A;
        if constexpr (MODE == 0) A = (m & 1) ? self : aggs[m >> 1];
        else                     A = (m < 3) ? aggs[m] : self;
        const u16* Bm = Bs + (size_t)m * CH * CH;

        short8 af[4];
        #pragma unroll
        for (int s = 0; s < 4; ++s)
            af[s] = ld8(&A[(size_t)(rb + c) * CH + s * 32 + q * 8]);

        #pragma unroll
        for (int s = 0; s < 4; ++s)
            #pragma unroll
            for (int nt = 0; nt < 8; ++nt) {
                short8 bv = ld8(&Bm[((size_t)(s * 8 + nt) * 64 + lane) * 8]);
                acc[nt] = mfma16(af[s], bv, acc[nt]);
            }

        if constexpr (MODE == 0) {
            if (m & 1) {
                const int t = m >> 1;
                float ss[4] = {0.f, 0.f, 0.f, 0.f};
                #pragma unroll
                for (int nt = 0; nt < 8; ++nt) {
                    float bf = bias[t * CH + nt * 16 + c];
                    #pragma unroll
                    for (int r = 0; r < 4; ++r) {
                        float v = acc[nt][r] + bf;
                        acc[nt][r] = v;
                        ss[r] += v * v;
                    }
                }
                #pragma unroll
                for (int msk = 1; msk < 16; msk <<= 1)
                    #pragma unroll
                    for (int r = 0; r < 4; ++r) ss[r] += __shfl_xor(ss[r], msk, 64);
                float sc[4];
                #pragma unroll
                for (int r = 0; r < 4; ++r)
                    sc[r] = 1.f / (3.f * fmaxf(sqrtf(ss[r]), 1e-12f));
                #pragma unroll
                for (int nt = 0; nt < 8; ++nt)
                    #pragma unroll
                    for (int r = 0; r < 4; ++r) {
                        res[nt][r] += acc[nt][r] * sc[r];
                        acc[nt][r] = 0.f;
                    }
            }
        }
    }

    if constexpr (MODE != 0) {
        #pragma unroll
        for (int nt = 0; nt < 8; ++nt) {
            float bv = bias[nt * 16 + c];
            #pragma unroll
            for (int r = 0; r < 4; ++r) res[nt][r] = acc[nt][r] + bv;
        }
    }

    if constexpr (MODE == 2) {
        #pragma unroll
        for (int nt = 0; nt < 8; ++nt)
            #pragma unroll
            for (int r = 0; r < 4; ++r) {
                int row = rb + q * 4 + r;
                if (row < nrows) outf[(size_t)row * CH + nt * 16 + c] = res[nt][r];
            }
        return;
    }

    // relu + LayerNorm (rows indexed by (q,r); reduce across the 16 c-lanes)
    float s1[4] = {0.f, 0.f, 0.f, 0.f}, s2[4] = {0.f, 0.f, 0.f, 0.f};
    #pragma unroll
    for (int nt = 0; nt < 8; ++nt)
        #pragma unroll
        for (int r = 0; r < 4; ++r) {
            float v = fmaxf(res[nt][r], 0.f);
            res[nt][r] = v;
            s1[r] += v;
            s2[r] += v * v;
        }
    #pragma unroll
    for (int msk = 1; msk < 16; msk <<= 1)
        #pragma unroll
        for (int r = 0; r < 4; ++r) {
            s1[r] += __shfl_xor(s1[r], msk, 64);
            s2[r] += __shfl_xor(s2[r], msk, 64);
        }
    float mu[4], rs[4];
    #pragma unroll
    for (int r = 0; r < 4; ++r) {
        mu[r] = s1[r] * (1.f / 128.f);
        float var = s2[r] * (1.f / 128.f) - mu[r] * mu[r];
        rs[r] = rsqrtf(var + LN_EPS);
    }
    #pragma unroll
    for (int nt = 0; nt < 8; ++nt) {
        float gv = lg[nt * 16 + c], bv = lb[nt * 16 + c];
        #pragma unroll
        for (int r = 0; r < 4; ++r) {
            int row = rb + q * 4 + r;
            if (row < nrows)
                outb[(size_t)row * CH + nt * 16 + c] =
                    f2bf((res[nt][r] - mu[r]) * rs[r] * gv + bv);
        }
    }
}

// ---------------------------------------------------------------------------
// CSR gather-mean (bf16): half-wave (32 lanes) per node, uint2 per lane,
// 2-edge unroll with dual accumulators. t = blockIdx.y (strided pointers).
// ---------------------------------------------------------------------------
__global__ __launch_bounds__(256) void agg_k(
    const u16* __restrict__ msg, const int* __restrict__ rowptr,
    const int* __restrict__ col, u16* __restrict__ agg, int n,
    int Ecap, unsigned long long aggstride)
{
    const int t = blockIdx.y;
    rowptr += (size_t)t * (n + 1);
    col += (size_t)t * Ecap;
    agg += (size_t)t * aggstride;

    int gid = blockIdx.x * 256 + threadIdx.x;
    int node = gid >> 5;
    int lane = threadIdx.x & 31;
    if (node >= n) return;
    int s = rowptr[node], e = rowptr[node + 1];
    const uint2* m64 = (const uint2*)msg;   // row = 32 uint2
    float a0 = 0.f, a1 = 0.f, a2 = 0.f, a3 = 0.f;
    float b0 = 0.f, b1 = 0.f, b2 = 0.f, b3 = 0.f;
    int j = s;
    for (; j + 2 <= e; j += 2) {
        int s0 = col[j], s1i = col[j + 1];
        uint2 v0 = m64[(size_t)s0 * 32 + lane];
        uint2 v1 = m64[(size_t)s1i * 32 + lane];
        a0 += bflo(v0.x); a1 += bfhi(v0.x); a2 += bflo(v0.y); a3 += bfhi(v0.y);
        b0 += bflo(v1.x); b1 += bfhi(v1.x); b2 += bflo(v1.y); b3 += bfhi(v1.y);
    }
    if (j < e) {
        int s0 = col[j];
        uint2 v0 = m64[(size_t)s0 * 32 + lane];
        a0 += bflo(v0.x); a1 += bfhi(v0.x); a2 += bflo(v0.y); a3 += bfhi(v0.y);
    }
    a0 += b0; a1 += b1; a2 += b2; a3 += b3;
    float inv = 1.f / (float)max(e - s, 1);
    uint2 o;
    o.x = (u32)f2bf(a0 * inv) | ((u32)f2bf(a1 * inv) << 16);
    o.y = (u32)f2bf(a2 * inv) | ((u32)f2bf(a3 * inv) << 16);
    ((uint2*)agg)[(size_t)node * 32 + lane] = o;
}

// ---------------------------------------------------------------------------
// CSR construction
// ---------------------------------------------------------------------------
__global__ __launch_bounds__(256) void hist_k(
    const int* __restrict__ edges, int* __restrict__ cnt, int E, int n)
{
    int t = blockIdx.y;
    int e = blockIdx.x * 256 + threadIdx.x;
    if (e >= E) return;
    int dst = edges[(size_t)t * 2 * E + E + e];
    atomicAdd(&cnt[t * n + dst], 1);
}

__global__ __launch_bounds__(256) void scan1_k(
    const int* __restrict__ cnt, int* __restrict__ bsum, int n, int nbs)
{
    int t = blockIdx.y, b = blockIdx.x;
    int i = b * 256 + threadIdx.x;
    int v = (i < n) ? cnt[t * n + i] : 0;
    #pragma unroll
    for (int m = 1; m < 64; m <<= 1) v += __shfl_xor(v, m, 64);
    __shared__ int wsum[4];
    if ((threadIdx.x & 63) == 0) wsum[threadIdx.x >> 6] = v;
    __syncthreads();
    if (threadIdx.x == 0) bsum[t * nbs + b] = wsum[0] + wsum[1] + wsum[2] + wsum[3];
}

__global__ __launch_bounds__(512) void scan2_k(int* __restrict__ bsum, int nbs, int nb)
{
    int t = blockIdx.x;
    int tid = threadIdx.x;
    __shared__ int sh[512];
    int v = (tid < nb) ? bsum[t * nbs + tid] : 0;
    sh[tid] = v;
    __syncthreads();
    for (int off = 1; off < 512; off <<= 1) {
        int x = (tid >= off) ? sh[tid - off] : 0;
        __syncthreads();
        sh[tid] += x;
        __syncthreads();
    }
    if (tid < nb) bsum[t * nbs + tid] = sh[tid] - v;
}

__global__ __launch_bounds__(256) void scan3_k(
    const int* __restrict__ cnt, const int* __restrict__ bsum,
    int* __restrict__ rowptr, int n, int nbs)
{
    int t = blockIdx.y, b = blockIdx.x;
    int tid = threadIdx.x;
    int i = b * 256 + tid;
    __shared__ int sh[256];
    int v = (i < n) ? cnt[t * n + i] : 0;
    sh[tid] = v;
    __syncthreads();
    for (int off = 1; off < 256; off <<= 1) {
        int x = (tid >= off) ? sh[tid - off] : 0;
        __syncthreads();
        sh[tid] += x;
        __syncthreads();
    }
    int excl = sh[tid] - v + bsum[t * nbs + b];
    if (i < n) rowptr[(size_t)t * (n + 1) + i] = excl;
    if (i == n - 1) rowptr[(size_t)t * (n + 1) + n] = excl + v;
}

__global__ __launch_bounds__(256) void fill_k(
    const int* __restrict__ edges, const int* __restrict__ rowptr,
    int* __restrict__ cnt2, int* __restrict__ colbuf, int E, int n)
{
    int t = blockIdx.y;
    int e = blockIdx.x * 256 + threadIdx.x;
    if (e >= E) return;
    int src = edges[(size_t)t * 2 * E + e];
    int dst = edges[(size_t)t * 2 * E + E + e];
    int pos = rowptr[(size_t)t * (n + 1) + dst] + atomicAdd(&cnt2[t * n + dst], 1);
    colbuf[(size_t)t * E + pos] = src;
}

// ---------------------------------------------------------------------------
extern "C" void kernel_launch(void* const* d_in, const int* in_sizes, int n_in,
                              void* d_out, int out_size, void* d_ws, size_t ws_size,
                              hipStream_t stream) {
    const float* x    = (const float*)d_in[0];
    const int*   edges= (const int*)d_in[1];
    const float* Wp   = (const float*)d_in[2];
    const float* bp   = (const float*)d_in[3];
    const float* Wl0  = (const float*)d_in[4];
    const float* bl0  = (const float*)d_in[5];
    const float* Wr0  = (const float*)d_in[6];
    const float* Wl   = (const float*)d_in[7];
    const float* bl   = (const float*)d_in[8];
    const float* Wr   = (const float*)d_in[9];
    const float* ln_g = (const float*)d_in[10];
    const float* ln_b = (const float*)d_in[11];
    float* out = (float*)d_out;

    const int n  = in_sizes[0] / CH;         // 100000
    const int E  = in_sizes[1] / (2 * ETC);  // 500000
    const int npad = ((n + 127) / 128) * 128;
    const int NBS = 512;
    const int nb = (n + 255) / 256;
    const size_t MS = (size_t)CH * CH;       // mat stride in u16

    // workspace layout
    char* p = (char*)d_ws;
    u16* xb   = (u16*)p;  p += (size_t)npad * CH * 2;
    u16* hs   = (u16*)p;  p += (size_t)npad * CH * 2;
    u16* agg  = (u16*)p;  p += (size_t)ETC * npad * CH * 2;
    u16* Bswz = (u16*)p;  p += 17 * MS * 2;
    float* bls = (float*)p; p += 256 * 4;
    int* cnt    = (int*)p;  p += (size_t)ETC * n * 4;
    int* rowptr = (int*)p;  p += (size_t)ETC * (n + 1) * 4;
    int* colbuf = (int*)p;  p += (size_t)ETC * E * 4;
    int* bsum   = (int*)p;

    const dim3 b256(256);
    const dim3 ge((E + 255) / 256, ETC);
    const dim3 gs(nb, ETC);
    const int gb16 = (n + 63) / 64;          // 16-row-wave GEMM blocks (1563)
    const int ga = (n * 32 + 255) / 256;     // agg blocks (half-wave/node)

    // ---- CSR build ----
    hipMemsetAsync(cnt, 0, (size_t)ETC * n * sizeof(int), stream);
    hist_k<<<ge, b256, 0, stream>>>(edges, cnt, E, n);
    scan1_k<<<gs, b256, 0, stream>>>(cnt, bsum, n, NBS);
    scan2_k<<<ETC, 512, 0, stream>>>(bsum, NBS, nb);
    scan3_k<<<gs, b256, 0, stream>>>(cnt, bsum, rowptr, n, NBS);
    hipMemsetAsync(cnt, 0, (size_t)ETC * n * sizeof(int), stream);
    fill_k<<<ge, b256, 0, stream>>>(edges, rowptr, cnt, colbuf, E, n);

    // ---- pack weights + cast x ----
    pack_w<<<136, b256, 0, stream>>>(Wp, Wl0, Wr0, Wl, Wr, bl, Bswz, bls);
    cast_x<<<(n * CH / 8 + 255) / 256, b256, 0, stream>>>(x, xb, n * CH);

    // ---- layer 0: per-type proj + gather; then fused combine ----
    for (int t = 0; t < ETC; ++t) {
        proj_k<<<gb16, b256, 0, stream>>>(xb, Bswz + (size_t)t * MS, bp + t * CH, hs, n);
        agg_k<<<dim3(ga, 1), b256, 0, stream>>>(hs, rowptr + (size_t)t * (n + 1),
                                                colbuf + (size_t)t * E,
                                                agg + (size_t)t * npad * CH, n, 0, 0ull);
    }
    combine_k<0><<<gb16, b256, 0, stream>>>(agg, agg + (size_t)npad * CH,
                                            agg + (size_t)2 * npad * CH, xb,
                                            Bswz + 3 * MS, bl0, ln_g, ln_b, hs, nullptr, n);

    // ---- layer 1 ----
    agg_k<<<dim3(ga, ETC), b256, 0, stream>>>(hs, rowptr, colbuf, agg, n, E,
                                              (unsigned long long)npad * CH);
    combine_k<1><<<gb16, b256, 0, stream>>>(agg, agg + (size_t)npad * CH,
                                            agg + (size_t)2 * npad * CH, hs,
                                            Bswz + 9 * MS, bls, ln_g + CH, ln_b + CH,
                                            hs, nullptr, n);

    // ---- layer 2 (final, fp32 out) ----
    agg_k<<<dim3(ga, ETC), b256, 0, stream>>>(hs, rowptr, colbuf, agg, n, E,
                                              (unsigned long long)npad * CH);
    combine_k<2><<<gb16, b256, 0, stream>>>(agg, agg + (size_t)npad * CH,
                                            agg + (size_t)2 * npad * CH, hs,
                                            Bswz + 13 * MS, bls + CH, nullptr, nullptr,
                                            nullptr, out, n);
}

// Round 4
// 690.521 us; speedup vs baseline: 2.6361x; 1.1785x over previous
//
#include <hip/hip_runtime.h>
#include <math.h>

#define CH 128
#define ETC 3
#define LN_EPS 1e-5f

typedef unsigned short u16;
typedef unsigned int u32;
typedef __attribute__((ext_vector_type(8))) short short8;
typedef __attribute__((ext_vector_type(4))) float f32x4;

__device__ __forceinline__ u16 f2bf(float f) {
    u32 u = __float_as_uint(f);
    u += 0x7FFFu + ((u >> 16) & 1u);
    return (u16)(u >> 16);
}
__device__ __forceinline__ float bflo(u32 u) { return __uint_as_float(u << 16); }
__device__ __forceinline__ float bfhi(u32 u) { return __uint_as_float(u & 0xFFFF0000u); }

__device__ __forceinline__ f32x4 mfma16(short8 a, short8 b, f32x4 c) {
    return __builtin_amdgcn_mfma_f32_16x16x32_bf16(a, b, c, 0, 0, 0);
}
__device__ __forceinline__ short8 ld8(const u16* p) { return *(const short8*)p; }

// ---------------------------------------------------------------------------
// Pack weights: fp32 -> bf16, swizzled to per-lane MFMA B-fragment order.
// Layout: [mat][s(4)][nt(8)][lane(64)][j(8)]   (mat stride = CH*CH u16)
// mats 0-2: Wp_t | 3-8: (Wl0_t, Wr0_t) pairs | 9-11: Wl[0,t]/3 | 12: sum(Wr[0,t])/3
// | 13-15: Wl[1,t]/3 | 16: sum(Wr[1,t])/3.  Also bls[2][128] = sum_t bl[l,t]/3.
// B fragment: lane(q=lane>>4,c=lane&15) holds B[k=s*32+q*8+j][n=nt*16+c]
// ---------------------------------------------------------------------------
__global__ __launch_bounds__(256) void pack_w(
    const float* __restrict__ Wp, const float* __restrict__ Wl0,
    const float* __restrict__ Wr0, const float* __restrict__ Wl,
    const float* __restrict__ Wr, const float* __restrict__ bl,
    u16* __restrict__ Bswz, float* __restrict__ bls)
{
    if (blockIdx.x == 0) {
        int l = threadIdx.x >> 7, i = threadIdx.x & 127;
        bls[threadIdx.x] = (bl[((size_t)l * ETC + 0) * CH + i] +
                            bl[((size_t)l * ETC + 1) * CH + i] +
                            bl[((size_t)l * ETC + 2) * CH + i]) * (1.f / 3.f);
    }
    int grp = blockIdx.x * 256 + threadIdx.x;   // ((mat*4+s)*8+nt)*64 + lane
    if (grp >= 17 * 2048) return;
    int lane = grp & 63;
    int t1 = grp >> 6;
    int nt = t1 & 7, t2 = t1 >> 3;
    int s = t2 & 3, mat = t2 >> 2;
    int q = lane >> 4, c = lane & 15;
    int nn = nt * 16 + c;

    const float* s0;
    const float* s1 = nullptr;
    const float* s2 = nullptr;
    float scale = 1.f;
    if (mat < 3) {
        s0 = Wp + (size_t)mat * CH * CH;
    } else if (mat < 9) {
        int t = (mat - 3) >> 1;
        s0 = ((mat - 3) & 1) ? Wr0 + (size_t)t * CH * CH : Wl0 + (size_t)t * CH * CH;
    } else {
        int l = (mat < 13) ? 0 : 1;
        int mm = mat - (l ? 13 : 9);
        scale = 1.f / 3.f;
        if (mm < 3) s0 = Wl + ((size_t)l * ETC + mm) * CH * CH;
        else {
            s0 = Wr + ((size_t)l * ETC + 0) * CH * CH;
            s1 = s0 + CH * CH;
            s2 = s1 + CH * CH;
        }
    }
    short8 o;
    #pragma unroll
    for (int j = 0; j < 8; ++j) {
        int k = s * 32 + q * 8 + j;
        float v = s0[(size_t)k * CH + nn];
        if (s1) v += s1[(size_t)k * CH + nn] + s2[(size_t)k * CH + nn];
        o[j] = (short)f2bf(v * scale);
    }
    *(short8*)&Bswz[(size_t)grp * 8] = o;
}

// ---------------------------------------------------------------------------
__global__ __launch_bounds__(256) void cast_x(
    const float* __restrict__ x, u16* __restrict__ xb, int total)
{
    int i = (blockIdx.x * 256 + threadIdx.x) * 8;
    if (i >= total) return;
    short8 o;
    #pragma unroll
    for (int j = 0; j < 8; ++j) o[j] = (short)f2bf(x[i + j]);
    *(short8*)&xb[i] = o;
}

// ---------------------------------------------------------------------------
// Fused layer GEMM: B staged in LDS per mat, RF row-frags (16 rows) per wave.
// MODE 0: layer0 (6 mats: (Wl0_t,Wr0_t) pairs; per-type L2-rownorm; relu+LN)
// MODE 1: mid (4 mats; +bls; relu+LN -> bf16)
// MODE 2: final (4 mats; +bls; fp32 out)
// MODE 3: proj (1 mat; +bias; relu -> bf16)
// Block = 256 thr = 4 waves; rows/block = 4 * RF * 16.
// ---------------------------------------------------------------------------
template<int MODE, int RF>
__global__ __launch_bounds__(256, 2) void combine_k(
    const u16* __restrict__ agg0, const u16* __restrict__ agg1,
    const u16* __restrict__ agg2, const u16* __restrict__ self,
    const u16* __restrict__ Bs, const float* __restrict__ bias,
    const float* __restrict__ lg, const float* __restrict__ lb,
    u16* __restrict__ outb, float* __restrict__ outf, int nrows)
{
    __shared__ __align__(16) u16 Bsh[CH * CH];   // 32 KB, one mat
    const int tid = threadIdx.x;
    const int w = tid >> 6, lane = tid & 63;
    const int q = lane >> 4, c = lane & 15;
    const int rbase = (blockIdx.x * 4 + w) * (RF * 16);
    const u16* aggs[3] = {agg0, agg1, agg2};
    constexpr int NM = (MODE == 0) ? 6 : ((MODE == 3) ? 1 : 4);

    f32x4 acc[RF][8] = {};
    f32x4 res[RF][8] = {};

    #pragma unroll
    for (int m = 0; m < NM; ++m) {
        // ---- stage B_m into LDS (whole block) ----
        __syncthreads();
        const u16* bsrc = Bs + (size_t)m * CH * CH;
        #pragma unroll
        for (int i = 0; i < 8; ++i)
            *(short8*)&Bsh[(i * 256 + tid) * 8] = ld8(&bsrc[(i * 256 + tid) * 8]);
        __syncthreads();

        const u16* A;
        if constexpr (MODE == 0)      A = (m & 1) ? self : aggs[m >> 1];
        else if constexpr (MODE == 3) A = self;
        else                          A = (m < 3) ? aggs[m] : self;

        #pragma unroll
        for (int s = 0; s < 4; ++s) {
            short8 af[RF];
            #pragma unroll
            for (int rf = 0; rf < RF; ++rf)
                af[rf] = ld8(&A[(size_t)(rbase + rf * 16 + c) * CH + s * 32 + q * 8]);
            #pragma unroll
            for (int nt = 0; nt < 8; ++nt) {
                short8 bv = *(const short8*)&Bsh[((size_t)(s * 8 + nt) * 64 + lane) * 8];
                #pragma unroll
                for (int rf = 0; rf < RF; ++rf)
                    acc[rf][nt] = mfma16(af[rf], bv, acc[rf][nt]);
            }
        }

        if constexpr (MODE == 0) {
            if (m & 1) {   // finished a (Wl0_t, Wr0_t) pair: rownorm + accumulate
                const int t = m >> 1;
                #pragma unroll
                for (int rf = 0; rf < RF; ++rf) {
                    float ss[4] = {0.f, 0.f, 0.f, 0.f};
                    #pragma unroll
                    for (int nt = 0; nt < 8; ++nt) {
                        float bf = bias[t * CH + nt * 16 + c];
                        #pragma unroll
                        for (int r = 0; r < 4; ++r) {
                            float v = acc[rf][nt][r] + bf;
                            acc[rf][nt][r] = v;
                            ss[r] += v * v;
                        }
                    }
                    #pragma unroll
                    for (int msk = 1; msk < 16; msk <<= 1)
                        #pragma unroll
                        for (int r = 0; r < 4; ++r) ss[r] += __shfl_xor(ss[r], msk, 64);
                    float sc[4];
                    #pragma unroll
                    for (int r = 0; r < 4; ++r)
                        sc[r] = 1.f / (3.f * fmaxf(sqrtf(ss[r]), 1e-12f));
                    #pragma unroll
                    for (int nt = 0; nt < 8; ++nt)
                        #pragma unroll
                        for (int r = 0; r < 4; ++r) {
                            res[rf][nt][r] += acc[rf][nt][r] * sc[r];
                            acc[rf][nt][r] = 0.f;
                        }
                }
            }
        }
    }

    if constexpr (MODE != 0) {
        #pragma unroll
        for (int nt = 0; nt < 8; ++nt) {
            float bv = bias[nt * 16 + c];
            #pragma unroll
            for (int rf = 0; rf < RF; ++rf)
                #pragma unroll
                for (int r = 0; r < 4; ++r) res[rf][nt][r] = acc[rf][nt][r] + bv;
        }
    }

    if constexpr (MODE == 2) {
        #pragma unroll
        for (int rf = 0; rf < RF; ++rf)
            #pragma unroll
            for (int nt = 0; nt < 8; ++nt)
                #pragma unroll
                for (int r = 0; r < 4; ++r) {
                    int row = rbase + rf * 16 + q * 4 + r;
                    if (row < nrows) outf[(size_t)row * CH + nt * 16 + c] = res[rf][nt][r];
                }
        return;
    }

    if constexpr (MODE == 3) {
        #pragma unroll
        for (int rf = 0; rf < RF; ++rf)
            #pragma unroll
            for (int nt = 0; nt < 8; ++nt)
                #pragma unroll
                for (int r = 0; r < 4; ++r) {
                    int row = rbase + rf * 16 + q * 4 + r;
                    outb[(size_t)row * CH + nt * 16 + c] = f2bf(fmaxf(res[rf][nt][r], 0.f));
                }
        return;
    }

    // MODE 0/1: relu + LayerNorm, per row-frag
    #pragma unroll
    for (int rf = 0; rf < RF; ++rf) {
        float s1[4] = {0.f, 0.f, 0.f, 0.f}, s2[4] = {0.f, 0.f, 0.f, 0.f};
        #pragma unroll
        for (int nt = 0; nt < 8; ++nt)
            #pragma unroll
            for (int r = 0; r < 4; ++r) {
                float v = fmaxf(res[rf][nt][r], 0.f);
                res[rf][nt][r] = v;
                s1[r] += v;
                s2[r] += v * v;
            }
        #pragma unroll
        for (int msk = 1; msk < 16; msk <<= 1)
            #pragma unroll
            for (int r = 0; r < 4; ++r) {
                s1[r] += __shfl_xor(s1[r], msk, 64);
                s2[r] += __shfl_xor(s2[r], msk, 64);
            }
        float mu[4], rs[4];
        #pragma unroll
        for (int r = 0; r < 4; ++r) {
            mu[r] = s1[r] * (1.f / 128.f);
            float var = s2[r] * (1.f / 128.f) - mu[r] * mu[r];
            rs[r] = rsqrtf(var + LN_EPS);
        }
        #pragma unroll
        for (int nt = 0; nt < 8; ++nt) {
            float gv = lg[nt * 16 + c], bv = lb[nt * 16 + c];
            #pragma unroll
            for (int r = 0; r < 4; ++r) {
                int row = rbase + rf * 16 + q * 4 + r;
                outb[(size_t)row * CH + nt * 16 + c] =
                    f2bf((res[rf][nt][r] - mu[r]) * rs[r] * gv + bv);
            }
        }
    }
}

// ---------------------------------------------------------------------------
// CSR gather-mean (bf16): half-wave (32 lanes) per node, uint2 per lane,
// 2-edge unroll with dual accumulators. t = blockIdx.y (strided pointers).
// ---------------------------------------------------------------------------
__global__ __launch_bounds__(256) void agg_k(
    const u16* __restrict__ msg, const int* __restrict__ rowptr,
    const int* __restrict__ col, u16* __restrict__ agg, int n,
    int Ecap, unsigned long long aggstride)
{
    const int t = blockIdx.y;
    rowptr += (size_t)t * (n + 1);
    col += (size_t)t * Ecap;
    agg += (size_t)t * aggstride;

    int gid = blockIdx.x * 256 + threadIdx.x;
    int node = gid >> 5;
    int lane = threadIdx.x & 31;
    if (node >= n) return;
    int s = rowptr[node], e = rowptr[node + 1];
    const uint2* m64 = (const uint2*)msg;   // row = 32 uint2
    float a0 = 0.f, a1 = 0.f, a2 = 0.f, a3 = 0.f;
    float b0 = 0.f, b1 = 0.f, b2 = 0.f, b3 = 0.f;
    int j = s;
    for (; j + 2 <= e; j += 2) {
        int s0 = col[j], s1i = col[j + 1];
        uint2 v0 = m64[(size_t)s0 * 32 + lane];
        uint2 v1 = m64[(size_t)s1i * 32 + lane];
        a0 += bflo(v0.x); a1 += bfhi(v0.x); a2 += bflo(v0.y); a3 += bfhi(v0.y);
        b0 += bflo(v1.x); b1 += bfhi(v1.x); b2 += bflo(v1.y); b3 += bfhi(v1.y);
    }
    if (j < e) {
        int s0 = col[j];
        uint2 v0 = m64[(size_t)s0 * 32 + lane];
        a0 += bflo(v0.x); a1 += bfhi(v0.x); a2 += bflo(v0.y); a3 += bfhi(v0.y);
    }
    a0 += b0; a1 += b1; a2 += b2; a3 += b3;
    float inv = 1.f / (float)max(e - s, 1);
    uint2 o;
    o.x = (u32)f2bf(a0 * inv) | ((u32)f2bf(a1 * inv) << 16);
    o.y = (u32)f2bf(a2 * inv) | ((u32)f2bf(a3 * inv) << 16);
    ((uint2*)agg)[(size_t)node * 32 + lane] = o;
}

// ---------------------------------------------------------------------------
// CSR construction
// ---------------------------------------------------------------------------
__global__ __launch_bounds__(256) void hist_k(
    const int* __restrict__ edges, int* __restrict__ cnt, int E, int n)
{
    int t = blockIdx.y;
    int e = blockIdx.x * 256 + threadIdx.x;
    if (e >= E) return;
    int dst = edges[(size_t)t * 2 * E + E + e];
    atomicAdd(&cnt[t * n + dst], 1);
}

__global__ __launch_bounds__(256) void scan1_k(
    const int* __restrict__ cnt, int* __restrict__ bsum, int n, int nbs)
{
    int t = blockIdx.y, b = blockIdx.x;
    int i = b * 256 + threadIdx.x;
    int v = (i < n) ? cnt[t * n + i] : 0;
    #pragma unroll
    for (int m = 1; m < 64; m <<= 1) v += __shfl_xor(v, m, 64);
    __shared__ int wsum[4];
    if ((threadIdx.x & 63) == 0) wsum[threadIdx.x >> 6] = v;
    __syncthreads();
    if (threadIdx.x == 0) bsum[t * nbs + b] = wsum[0] + wsum[1] + wsum[2] + wsum[3];
}

__global__ __launch_bounds__(512) void scan2_k(int* __restrict__ bsum, int nbs, int nb)
{
    int t = blockIdx.x;
    int tid = threadIdx.x;
    __shared__ int sh[512];
    int v = (tid < nb) ? bsum[t * nbs + tid] : 0;
    sh[tid] = v;
    __syncthreads();
    for (int off = 1; off < 512; off <<= 1) {
        int x = (tid >= off) ? sh[tid - off] : 0;
        __syncthreads();
        sh[tid] += x;
        __syncthreads();
    }
    if (tid < nb) bsum[t * nbs + tid] = sh[tid] - v;
}

__global__ __launch_bounds__(256) void scan3_k(
    const int* __restrict__ cnt, const int* __restrict__ bsum,
    int* __restrict__ rowptr, int n, int nbs)
{
    int t = blockIdx.y, b = blockIdx.x;
    int tid = threadIdx.x;
    int i = b * 256 + tid;
    __shared__ int sh[256];
    int v = (i < n) ? cnt[t * n + i] : 0;
    sh[tid] = v;
    __syncthreads();
    for (int off = 1; off < 256; off <<= 1) {
        int x = (tid >= off) ? sh[tid - off] : 0;
        __syncthreads();
        sh[tid] += x;
        __syncthreads();
    }
    int excl = sh[tid] - v + bsum[t * nbs + b];
    if (i < n) rowptr[(size_t)t * (n + 1) + i] = excl;
    if (i == n - 1) rowptr[(size_t)t * (n + 1) + n] = excl + v;
}

__global__ __launch_bounds__(256) void fill_k(
    const int* __restrict__ edges, const int* __restrict__ rowptr,
    int* __restrict__ cnt2, int* __restrict__ colbuf, int E, int n)
{
    int t = blockIdx.y;
    int e = blockIdx.x * 256 + threadIdx.x;
    if (e >= E) return;
    int src = edges[(size_t)t * 2 * E + e];
    int dst = edges[(size_t)t * 2 * E + E + e];
    int pos = rowptr[(size_t)t * (n + 1) + dst] + atomicAdd(&cnt2[t * n + dst], 1);
    colbuf[(size_t)t * E + pos] = src;
}

// ---------------------------------------------------------------------------
extern "C" void kernel_launch(void* const* d_in, const int* in_sizes, int n_in,
                              void* d_out, int out_size, void* d_ws, size_t ws_size,
                              hipStream_t stream) {
    const float* x    = (const float*)d_in[0];
    const int*   edges= (const int*)d_in[1];
    const float* Wp   = (const float*)d_in[2];
    const float* bp   = (const float*)d_in[3];
    const float* Wl0  = (const float*)d_in[4];
    const float* bl0  = (const float*)d_in[5];
    const float* Wr0  = (const float*)d_in[6];
    const float* Wl   = (const float*)d_in[7];
    const float* bl   = (const float*)d_in[8];
    const float* Wr   = (const float*)d_in[9];
    const float* ln_g = (const float*)d_in[10];
    const float* ln_b = (const float*)d_in[11];
    float* out = (float*)d_out;

    const int n  = in_sizes[0] / CH;         // 100000
    const int E  = in_sizes[1] / (2 * ETC);  // 500000
    const int npad = ((n + 255) / 256) * 256; // 100096 (also /128 exact)
    const int NBS = 512;
    const int nb = (n + 255) / 256;
    const size_t MS = (size_t)CH * CH;       // mat stride in u16

    // workspace layout
    char* p = (char*)d_ws;
    u16* xb   = (u16*)p;  p += (size_t)npad * CH * 2;
    u16* hs   = (u16*)p;  p += (size_t)npad * CH * 2;
    u16* agg  = (u16*)p;  p += (size_t)ETC * npad * CH * 2;
    u16* Bswz = (u16*)p;  p += 17 * MS * 2;
    float* bls = (float*)p; p += 256 * 4;
    int* cnt    = (int*)p;  p += (size_t)ETC * n * 4;
    int* rowptr = (int*)p;  p += (size_t)ETC * (n + 1) * 4;
    int* colbuf = (int*)p;  p += (size_t)ETC * E * 4;
    int* bsum   = (int*)p;

    const dim3 b256(256);
    const dim3 ge((E + 255) / 256, ETC);
    const dim3 gs(nb, ETC);
    const int gb2 = (n + 127) / 128;         // MODE0 blocks (RF=2, 128 rows)
    const int gb4 = (n + 255) / 256;         // RF=4 blocks (256 rows)
    const int ga = (n * 32 + 255) / 256;     // agg blocks (half-wave/node)

    // ---- CSR build ----
    hipMemsetAsync(cnt, 0, (size_t)ETC * n * sizeof(int), stream);
    hist_k<<<ge, b256, 0, stream>>>(edges, cnt, E, n);
    scan1_k<<<gs, b256, 0, stream>>>(cnt, bsum, n, NBS);
    scan2_k<<<ETC, 512, 0, stream>>>(bsum, NBS, nb);
    scan3_k<<<gs, b256, 0, stream>>>(cnt, bsum, rowptr, n, NBS);
    hipMemsetAsync(cnt, 0, (size_t)ETC * n * sizeof(int), stream);
    fill_k<<<ge, b256, 0, stream>>>(edges, rowptr, cnt, colbuf, E, n);

    // ---- pack weights + cast x ----
    pack_w<<<136, b256, 0, stream>>>(Wp, Wl0, Wr0, Wl, Wr, bl, Bswz, bls);
    cast_x<<<(n * CH / 8 + 255) / 256, b256, 0, stream>>>(x, xb, n * CH);

    // ---- layer 0: per-type proj + gather; then fused combine ----
    for (int t = 0; t < ETC; ++t) {
        combine_k<3, 4><<<gb4, b256, 0, stream>>>(
            nullptr, nullptr, nullptr, xb, Bswz + (size_t)t * MS, bp + t * CH,
            nullptr, nullptr, hs, nullptr, n);
        agg_k<<<dim3(ga, 1), b256, 0, stream>>>(hs, rowptr + (size_t)t * (n + 1),
                                                colbuf + (size_t)t * E,
                                                agg + (size_t)t * npad * CH, n, 0, 0ull);
    }
    combine_k<0, 2><<<gb2, b256, 0, stream>>>(agg, agg + (size_t)npad * CH,
                                              agg + (size_t)2 * npad * CH, xb,
                                              Bswz + 3 * MS, bl0, ln_g, ln_b, hs, nullptr, n);

    // ---- layer 1 ----
    agg_k<<<dim3(ga, ETC), b256, 0, stream>>>(hs, rowptr, colbuf, agg, n, E,
                                              (unsigned long long)npad * CH);
    combine_k<1, 4><<<gb4, b256, 0, stream>>>(agg, agg + (size_t)npad * CH,
                                              agg + (size_t)2 * npad * CH, hs,
                                              Bswz + 9 * MS, bls, ln_g + CH, ln_b + CH,
                                              hs, nullptr, n);

    // ---- layer 2 (final, fp32 out) ----
    agg_k<<<dim3(ga, ETC), b256, 0, stream>>>(hs, rowptr, colbuf, agg, n, E,
                                              (unsigned long long)npad * CH);
    combine_k<2, 4><<<gb4, b256, 0, stream>>>(agg, agg + (size_t)npad * CH,
                                              agg + (size_t)2 * npad * CH, hs,
                                              Bswz + 13 * MS, bls + CH, nullptr, nullptr,
                                              nullptr, out, n);
}